// Round 1
// baseline (417.007 us; speedup 1.0000x reference)
//
#include <hip/hip_runtime.h>
#include <stdint.h>

// ---------------------------------------------------------------------------
// Problem constants
// ---------------------------------------------------------------------------
#define NB   7
#define SIN  16
#define DD   128
#define BB   32
#define TT   2048
#define TM   64          // t-rows per block
#define KMAX 31

// LDS strides (elements, ushort/bf16). All multiples of 8 (16B-aligned rows).
#define XWS  40          // x window stride  (95 rows)
#define HS   136         // h / z / m buffers (64 rows)
#define US   264         // u buffer (64 rows)
#define PS   72          // p buffer (aliases u)

// ws (bf16 element offsets)
#define O_CWT 0           // [7][128][512]
#define O_W1T 458752      // [7][256][128]
#define O_W2T 688128      // [7][128][256]
#define O_PT  917504      // [7][64][128]
#define O_M1T 974848      // [128][448]
#define O_M2T 1032192     // [16][128]
#define W_TOTAL 1034240

typedef short v8s __attribute__((ext_vector_type(8)));
typedef float v4f __attribute__((ext_vector_type(4)));

__device__ __forceinline__ unsigned short f2b(float f) {
    unsigned u = __float_as_uint(f);
    u += 0x7fffu + ((u >> 16) & 1u);          // round-to-nearest-even
    return (unsigned short)(u >> 16);
}
__device__ __forceinline__ float b2f(unsigned short h) {
    return __uint_as_float(((unsigned)h) << 16);
}
__device__ __forceinline__ float gelu_fast(float x) {   // sigmoid approx (inner FFN only)
    return x / (1.f + __expf(-1.702f * x));
}
__device__ __forceinline__ float gelu_exact(float x) {  // final mix gelu
    return 0.5f * x * (1.f + erff(x * 0.70710678118654752f));
}

// ---------------------------------------------------------------------------
// Weight prep: fp32 -> bf16, transposed to B-fragment-friendly layouts
// ---------------------------------------------------------------------------
__global__ void prep_weights(const float* __restrict__ conv_w,
                             const float* __restrict__ ffn_w1,
                             const float* __restrict__ ffn_w2,
                             const float* __restrict__ proj_w,
                             const float* __restrict__ mix_w1,
                             const float* __restrict__ mix_w2,
                             unsigned short* __restrict__ wsb) {
    for (int i = blockIdx.x * 256 + threadIdx.x; i < W_TOTAL; i += gridDim.x * 256) {
        float v;
        int o = i;
        if (o < O_W1T) {                       // cwT[n][d][kf], kf = k*16+s (k==31 -> 0)
            int n = o / (128 * 512); int r = o % (128 * 512);
            int d = r / 512; int kf = r % 512;
            int k = kf >> 4, s = kf & 15;
            v = (k < KMAX) ? conv_w[((n * KMAX + k) * SIN + s) * DD + d] : 0.f;
        } else if ((o -= O_W1T) < (O_W2T - O_W1T)) {   // w1T[n][e][k] = ffn_w1[n][k][e]
            int n = o / (256 * 128); int r = o % (256 * 128);
            int e = r / 128; int k = r % 128;
            v = ffn_w1[(n * 128 + k) * 256 + e];
        } else if ((o -= (O_W2T - O_W1T)) < (O_PT - O_W2T)) { // w2T[n][d][e] = ffn_w2[n][e][d]
            int n = o / (128 * 256); int r = o % (128 * 256);
            int d = r / 256; int e = r % 256;
            v = ffn_w2[(n * 256 + e) * 128 + d];
        } else if ((o -= (O_PT - O_W2T)) < (O_M1T - O_PT)) {  // pT[n][j][k] = proj_w[n][k][j]
            int n = o / (64 * 128); int r = o % (64 * 128);
            int j = r / 128; int k = r % 128;
            v = proj_w[(n * 128 + k) * 64 + j];
        } else if ((o -= (O_M1T - O_PT)) < (O_M2T - O_M1T)) { // m1T[c][kk] = mix_w1[kk][c]
            int c = o / 448; int kk = o % 448;
            v = mix_w1[kk * 128 + c];
        } else {                                              // m2T[o16][c] = mix_w2[c][o16]
            o -= (O_M2T - O_M1T);
            int o16 = o / 128; int c = o % 128;
            v = mix_w2[c * 16 + o16];
        }
        wsb[i] = f2b(v);
    }
}

// ---------------------------------------------------------------------------
// Fused main kernel: one block = 64 t-rows of one batch, full pipeline
// ---------------------------------------------------------------------------
__global__ __launch_bounds__(256, 2)
void fused_main(const float* __restrict__ x,
                const float* __restrict__ conv_b,
                const float* __restrict__ dec_g, const float* __restrict__ dec_b,
                const float* __restrict__ n2_g,  const float* __restrict__ n2_b,
                const float* __restrict__ ffn_b1, const float* __restrict__ ffn_b2,
                const float* __restrict__ proj_b,
                const float* __restrict__ mix_b1, const float* __restrict__ mix_b2,
                const unsigned short* __restrict__ wsb,
                float* __restrict__ out) {
    __shared__ __align__(16) unsigned short xw[95 * XWS];    //  7,600 B
    __shared__ __align__(16) unsigned short hbuf[TM * HS];   // 17,408 B
    __shared__ __align__(16) unsigned short zbuf[TM * HS];   // 17,408 B
    __shared__ __align__(16) unsigned short ubuf[TM * US];   // 33,792 B  (aliased by pb)

    const int tid  = threadIdx.x;
    const int lane = tid & 63;
    const int w    = tid >> 6;       // wave 0..3
    const int l16  = lane & 15;
    const int quad = lane >> 4;      // 0..3
    const int bb   = blockIdx.x >> 5;
    const int t0   = (blockIdx.x & 31) * TM;

    const unsigned short* cwT = wsb + O_CWT;
    const unsigned short* w1T = wsb + O_W1T;
    const unsigned short* w2T = wsb + O_W2T;
    const unsigned short* pT  = wsb + O_PT;
    const unsigned short* m1T = wsb + O_M1T;
    const unsigned short* m2T = wsb + O_M2T;

    // ---- S0: stage x window (rows t0-15 .. t0+78), bf16 ----
    for (int i = tid; i < 95 * SIN; i += 256) {
        int r = i >> 4, s = i & 15;
        int t = t0 + r - 15;
        float v = (t >= 0 && t < TT) ? x[((long)bb * TT + t) * SIN + s] : 0.f;
        xw[r * XWS + s] = f2b(v);
    }

    v4f macc[4][2];                  // persistent mix1 accumulators (cols w*32..w*32+31)
    #pragma unroll
    for (int a = 0; a < 4; a++)
        #pragma unroll
        for (int c = 0; c < 2; c++)
            macc[a][c] = (v4f){0.f, 0.f, 0.f, 0.f};

    __syncthreads();

    // per-band conv K-ranges (32-aligned, covering the non-zero taps)
    static const int lo_tab[NB] = {0, 64, 128, 160, 192, 192, 224};
    static const int hi_tab[NB] = {512, 416, 384, 352, 320, 288, 288};

    for (int n = 0; n < NB; ++n) {
        // ================= S1: conv (im2col GEMM), M=64 K=K~n N=128 =================
        {
            v4f acc[4][2];
            #pragma unroll
            for (int mt = 0; mt < 4; mt++)
                #pragma unroll
                for (int nt = 0; nt < 2; nt++) acc[mt][nt] = (v4f){0.f, 0.f, 0.f, 0.f};
            const int colb = w * 32;
            const int lo = lo_tab[n], hi = hi_tab[n];
            for (int kf = lo; kf < hi; kf += 32) {
                const int tap  = (kf >> 4) + (quad >> 1);
                const int scol = (quad & 1) * 8;
                v8s a[4], bf[2];
                #pragma unroll
                for (int mt = 0; mt < 4; mt++)
                    a[mt] = *reinterpret_cast<const v8s*>(&xw[(mt * 16 + l16 + tap) * XWS + scol]);
                #pragma unroll
                for (int nt = 0; nt < 2; nt++)
                    bf[nt] = *reinterpret_cast<const v8s*>(
                        &cwT[(size_t)(n * 128 + colb + nt * 16 + l16) * 512 + kf + quad * 8]);
                #pragma unroll
                for (int mt = 0; mt < 4; mt++)
                    #pragma unroll
                    for (int nt = 0; nt < 2; nt++)
                        acc[mt][nt] = __builtin_amdgcn_mfma_f32_16x16x32_bf16(a[mt], bf[nt], acc[mt][nt], 0, 0, 0);
            }
            #pragma unroll
            for (int nt = 0; nt < 2; nt++) {
                const int col = colb + nt * 16 + l16;
                const float bias = conv_b[n * 128 + col];
                #pragma unroll
                for (int mt = 0; mt < 4; mt++)
                    #pragma unroll
                    for (int r = 0; r < 4; r++)
                        hbuf[(mt * 16 + quad * 4 + r) * HS + col] = f2b(acc[mt][nt][r] + bias);
            }
        }
        __syncthreads();

        // ================= S2: dual LayerNorm (4 lanes per row) =================
        {
            const int row = tid >> 2, q = tid & 3;
            float v[32], s1 = 0.f, s2 = 0.f;
            #pragma unroll
            for (int c8 = 0; c8 < 4; c8++) {
                v8s t8 = *reinterpret_cast<const v8s*>(&hbuf[row * HS + q * 32 + c8 * 8]);
                #pragma unroll
                for (int j = 0; j < 8; j++) {
                    float f = b2f((unsigned short)t8[j]);
                    v[c8 * 8 + j] = f; s1 += f; s2 += f * f;
                }
            }
            s1 += __shfl_xor(s1, 1); s2 += __shfl_xor(s2, 1);
            s1 += __shfl_xor(s1, 2); s2 += __shfl_xor(s2, 2);
            const float m1 = s1 * (1.f / 128.f);
            const float rs = rsqrtf(s2 * (1.f / 128.f) - m1 * m1 + 1e-5f);
            const float4* dg4 = (const float4*)(dec_g + n * 128);
            const float4* db4 = (const float4*)(dec_b + n * 128);
            float hv[32], t1 = 0.f, t2 = 0.f;
            #pragma unroll
            for (int c4 = 0; c4 < 8; c4++) {
                float4 g4 = dg4[q * 8 + c4], b4 = db4[q * 8 + c4];
                float ga[4] = {g4.x, g4.y, g4.z, g4.w};
                float ba[4] = {b4.x, b4.y, b4.z, b4.w};
                #pragma unroll
                for (int j = 0; j < 4; j++) {
                    float h = (v[c4 * 4 + j] - m1) * rs * ga[j] + ba[j];
                    hv[c4 * 4 + j] = h; t1 += h; t2 += h * h;
                    hbuf[row * HS + q * 32 + c4 * 4 + j] = f2b(h);
                }
            }
            t1 += __shfl_xor(t1, 1); t2 += __shfl_xor(t2, 1);
            t1 += __shfl_xor(t1, 2); t2 += __shfl_xor(t2, 2);
            const float m2 = t1 * (1.f / 128.f);
            const float rs2 = rsqrtf(t2 * (1.f / 128.f) - m2 * m2 + 1e-5f);
            const float4* ng4 = (const float4*)(n2_g + n * 128);
            const float4* nb4 = (const float4*)(n2_b + n * 128);
            #pragma unroll
            for (int c4 = 0; c4 < 8; c4++) {
                float4 g4 = ng4[q * 8 + c4], b4 = nb4[q * 8 + c4];
                float ga[4] = {g4.x, g4.y, g4.z, g4.w};
                float ba[4] = {b4.x, b4.y, b4.z, b4.w};
                #pragma unroll
                for (int j = 0; j < 4; j++) {
                    float z = (hv[c4 * 4 + j] - m2) * rs2 * ga[j] + ba[j];
                    zbuf[row * HS + q * 32 + c4 * 4 + j] = f2b(z);
                }
            }
        }
        __syncthreads();

        // ================= S3: FFN1 + gelu, M=64 K=128 N=256 =================
        {
            v4f acc[4][4];
            #pragma unroll
            for (int mt = 0; mt < 4; mt++)
                #pragma unroll
                for (int et = 0; et < 4; et++) acc[mt][et] = (v4f){0.f, 0.f, 0.f, 0.f};
            const int eb = w * 64;
            #pragma unroll
            for (int kb = 0; kb < 128; kb += 32) {
                v8s a[4], bf[4];
                #pragma unroll
                for (int mt = 0; mt < 4; mt++)
                    a[mt] = *reinterpret_cast<const v8s*>(&zbuf[(mt * 16 + l16) * HS + kb + quad * 8]);
                #pragma unroll
                for (int et = 0; et < 4; et++)
                    bf[et] = *reinterpret_cast<const v8s*>(
                        &w1T[(size_t)(n * 256 + eb + et * 16 + l16) * 128 + kb + quad * 8]);
                #pragma unroll
                for (int mt = 0; mt < 4; mt++)
                    #pragma unroll
                    for (int et = 0; et < 4; et++)
                        acc[mt][et] = __builtin_amdgcn_mfma_f32_16x16x32_bf16(a[mt], bf[et], acc[mt][et], 0, 0, 0);
            }
            #pragma unroll
            for (int et = 0; et < 4; et++) {
                const int e = eb + et * 16 + l16;
                const float bias = ffn_b1[n * 256 + e];
                #pragma unroll
                for (int mt = 0; mt < 4; mt++)
                    #pragma unroll
                    for (int r = 0; r < 4; r++)
                        ubuf[(mt * 16 + quad * 4 + r) * US + e] = f2b(gelu_fast(acc[mt][et][r] + bias));
            }
        }
        __syncthreads();

        // ================= S4: FFN2 + residual, M=64 K=256 N=128 =================
        {
            v4f acc[4][2];
            #pragma unroll
            for (int mt = 0; mt < 4; mt++)
                #pragma unroll
                for (int nt = 0; nt < 2; nt++) acc[mt][nt] = (v4f){0.f, 0.f, 0.f, 0.f};
            const int dbs = w * 32;
            #pragma unroll
            for (int kb = 0; kb < 256; kb += 32) {
                v8s a[4], bf[2];
                #pragma unroll
                for (int mt = 0; mt < 4; mt++)
                    a[mt] = *reinterpret_cast<const v8s*>(&ubuf[(mt * 16 + l16) * US + kb + quad * 8]);
                #pragma unroll
                for (int nt = 0; nt < 2; nt++)
                    bf[nt] = *reinterpret_cast<const v8s*>(
                        &w2T[(size_t)(n * 128 + dbs + nt * 16 + l16) * 256 + kb + quad * 8]);
                #pragma unroll
                for (int mt = 0; mt < 4; mt++)
                    #pragma unroll
                    for (int nt = 0; nt < 2; nt++)
                        acc[mt][nt] = __builtin_amdgcn_mfma_f32_16x16x32_bf16(a[mt], bf[nt], acc[mt][nt], 0, 0, 0);
            }
            #pragma unroll
            for (int nt = 0; nt < 2; nt++) {
                const int col = dbs + nt * 16 + l16;
                const float bias = ffn_b2[n * 128 + col];
                #pragma unroll
                for (int mt = 0; mt < 4; mt++)
                    #pragma unroll
                    for (int r = 0; r < 4; r++) {
                        const int row = mt * 16 + quad * 4 + r;
                        float bo = acc[mt][nt][r] + bias + b2f(hbuf[row * HS + col]);
                        zbuf[row * HS + col] = f2b(bo);
                    }
            }
        }
        __syncthreads();

        // ================= S5: proj, M=64 K=128 N=64 (16 cols per wave) =================
        {
            v4f acc[4];
            #pragma unroll
            for (int mt = 0; mt < 4; mt++) acc[mt] = (v4f){0.f, 0.f, 0.f, 0.f};
            const int j = w * 16 + l16;
            #pragma unroll
            for (int kb = 0; kb < 128; kb += 32) {
                v8s bf = *reinterpret_cast<const v8s*>(&pT[(size_t)(n * 64 + j) * 128 + kb + quad * 8]);
                #pragma unroll
                for (int mt = 0; mt < 4; mt++) {
                    v8s a = *reinterpret_cast<const v8s*>(&zbuf[(mt * 16 + l16) * HS + kb + quad * 8]);
                    acc[mt] = __builtin_amdgcn_mfma_f32_16x16x32_bf16(a, bf, acc[mt], 0, 0, 0);
                }
            }
            const float bias = proj_b[n * 64 + j];
            unsigned short* pb = ubuf;   // alias (u dead after S4)
            #pragma unroll
            for (int mt = 0; mt < 4; mt++)
                #pragma unroll
                for (int r = 0; r < 4; r++)
                    pb[(mt * 16 + quad * 4 + r) * PS + j] = f2b(acc[mt][r] + bias);
        }
        __syncthreads();

        // ================= S6: mix1 partial accumulate, M=64 K=64 N=128 =================
        {
            const unsigned short* pb = ubuf;
            #pragma unroll
            for (int kb = 0; kb < 64; kb += 32) {
                v8s a[4], bf[2];
                #pragma unroll
                for (int mt = 0; mt < 4; mt++)
                    a[mt] = *reinterpret_cast<const v8s*>(&pb[(mt * 16 + l16) * PS + kb + quad * 8]);
                #pragma unroll
                for (int nt = 0; nt < 2; nt++)
                    bf[nt] = *reinterpret_cast<const v8s*>(
                        &m1T[(size_t)(w * 32 + nt * 16 + l16) * 448 + n * 64 + kb + quad * 8]);
                #pragma unroll
                for (int mt = 0; mt < 4; mt++)
                    #pragma unroll
                    for (int nt = 0; nt < 2; nt++)
                        macc[mt][nt] = __builtin_amdgcn_mfma_f32_16x16x32_bf16(a[mt], bf[nt], macc[mt][nt], 0, 0, 0);
            }
        }
        // no barrier needed: next S1 writes hbuf (last read 2 barriers ago), reads xw/cwT
    }

    // ================= S7: m = gelu(macc + b1) -> zbuf (bf16) =================
    #pragma unroll
    for (int nt = 0; nt < 2; nt++) {
        const int col = w * 32 + nt * 16 + l16;
        const float bias = mix_b1[col];
        #pragma unroll
        for (int mt = 0; mt < 4; mt++)
            #pragma unroll
            for (int r = 0; r < 4; r++)
                zbuf[(mt * 16 + quad * 4 + r) * HS + col] = f2b(gelu_exact(macc[mt][nt][r] + bias));
    }
    __syncthreads();

    // ================= S8: mix2, M=64 K=128 N=16 (wave w -> rows w*16..) =================
    {
        v4f acc = (v4f){0.f, 0.f, 0.f, 0.f};
        #pragma unroll
        for (int kb = 0; kb < 128; kb += 32) {
            v8s a  = *reinterpret_cast<const v8s*>(&zbuf[(w * 16 + l16) * HS + kb + quad * 8]);
            v8s bf = *reinterpret_cast<const v8s*>(&m2T[(size_t)l16 * 128 + kb + quad * 8]);
            acc = __builtin_amdgcn_mfma_f32_16x16x32_bf16(a, bf, acc, 0, 0, 0);
        }
        const float bias = mix_b2[l16];
        #pragma unroll
        for (int r = 0; r < 4; r++) {
            const int row = w * 16 + quad * 4 + r;
            out[((long)bb * TT + t0 + row) * SIN + l16] = acc[r] + bias;
        }
    }
}

// ---------------------------------------------------------------------------
extern "C" void kernel_launch(void* const* d_in, const int* in_sizes, int n_in,
                              void* d_out, int out_size, void* d_ws, size_t ws_size,
                              hipStream_t stream) {
    (void)in_sizes; (void)n_in; (void)out_size; (void)ws_size;
    const float* x      = (const float*)d_in[0];
    const float* conv_w = (const float*)d_in[1];
    const float* conv_b = (const float*)d_in[2];
    const float* dec_g  = (const float*)d_in[3];
    const float* dec_b  = (const float*)d_in[4];
    const float* n2_g   = (const float*)d_in[5];
    const float* n2_b   = (const float*)d_in[6];
    const float* ffn_w1 = (const float*)d_in[7];
    const float* ffn_b1 = (const float*)d_in[8];
    const float* ffn_w2 = (const float*)d_in[9];
    const float* ffn_b2 = (const float*)d_in[10];
    const float* proj_w = (const float*)d_in[11];
    const float* proj_b = (const float*)d_in[12];
    const float* mix_w1 = (const float*)d_in[13];
    const float* mix_b1 = (const float*)d_in[14];
    const float* mix_w2 = (const float*)d_in[15];
    const float* mix_b2 = (const float*)d_in[16];
    unsigned short* wsb = (unsigned short*)d_ws;
    float* out = (float*)d_out;

    hipLaunchKernelGGL(prep_weights, dim3(512), dim3(256), 0, stream,
                       conv_w, ffn_w1, ffn_w2, proj_w, mix_w1, mix_w2, wsb);
    hipLaunchKernelGGL(fused_main, dim3(BB * (TT / TM)), dim3(256), 0, stream,
                       x, conv_b, dec_g, dec_b, n2_g, n2_b, ffn_b1, ffn_b2,
                       proj_b, mix_b1, mix_b2, wsb, out);
}